// Round 1
// baseline (1762.265 us; speedup 1.0000x reference)
//
#include <hip/hip_runtime.h>
#include <math.h>

#define BB 32
#define TT 512
#define IND 2048
#define DD 512
#define OD 29
#define WCOLS 64

// ---------------- zero-fill d_out ----------------
__global__ void k_zero(float* __restrict__ p, int n) {
  int n4 = n >> 2;
  int i = blockIdx.x * blockDim.x + threadIdx.x;
  int stride = gridDim.x * blockDim.x;
  float4 z = make_float4(0.f, 0.f, 0.f, 0.f);
  for (int j = i; j < n4; j += stride) ((float4*)p)[j] = z;
  int base = (n4 << 2) + i;
  if (base < n) p[base] = 0.f;
}

// ---------------- fold weights: Wt[2049][64] ----------------
// cols 0..28 : scale * W_in @ W_q^T     (G part)
// col  29    : scale * W_in @ b_q       (C part)
// cols 32..60: W_in @ W_out             (P part)
// row 2048   : same with b_in (bias row). Other cols = 0.
__global__ __launch_bounds__(64) void k_transform(
    const float* __restrict__ W_in, const float* __restrict__ b_in,
    const float* __restrict__ W_q,  const float* __restrict__ b_q,
    const float* __restrict__ W_out, float* __restrict__ Wt) {
  int i = blockIdx.x;          // 0..2048
  int c = threadIdx.x;         // 0..63
  const float* row = (i < IND) ? (W_in + (size_t)i * DD) : b_in;
  const float* m;
  int strd;
  bool valid = true, dscale = false;
  if (c < OD)                { m = W_q + (size_t)c * DD; strd = 1; dscale = true; }
  else if (c == OD)          { m = b_q;                  strd = 1; dscale = true; }
  else if (c >= 32 && c < 32 + OD) { m = W_out + (c - 32); strd = OD; }
  else                       { m = b_q; strd = 0; valid = false; }
  float acc = 0.f;
  #pragma unroll 4
  for (int d = 0; d < DD; ++d) acc += row[d] * m[(size_t)d * strd];
  if (dscale) acc *= (1.0f / sqrtf((float)DD));
  if (!valid) acc = 0.f;
  Wt[(size_t)i * WCOLS + c] = acc;
}

// ---------------- GPC = x @ Wt + bias ----------------
// 64 rows x 64 cols per block; 4 waves, wave cg owns 16 cols; lane = row.
// Wt read through readfirstlane-uniform pointer -> scalar loads.
__global__ __launch_bounds__(256) void k_gemm(
    const float* __restrict__ x, const float* __restrict__ Wt,
    float* __restrict__ GPC) {
  __shared__ float xt[128][65];
  int tid = threadIdx.x;
  int r = tid & 63;
  int cg16 = __builtin_amdgcn_readfirstlane((tid >> 6) << 4);
  int m0 = blockIdx.x << 6;
  int lr = tid >> 2, lc = tid & 3;
  const float* xl = x + (size_t)(m0 + lr) * IND;
  float4 a0 = make_float4(0,0,0,0), a1 = a0, a2 = a0, a3 = a0;
  for (int kk = 0; kk < IND; kk += 128) {
    __syncthreads();
    #pragma unroll
    for (int j = 0; j < 8; ++j) {
      int k = (lc + 4 * j) << 2;
      float4 v = *(const float4*)(xl + kk + k);
      xt[k + 0][lr] = v.x; xt[k + 1][lr] = v.y;
      xt[k + 2][lr] = v.z; xt[k + 3][lr] = v.w;
    }
    __syncthreads();
    const float* wb = Wt + (size_t)kk * WCOLS + cg16;
    #pragma unroll 4
    for (int k = 0; k < 128; ++k) {
      float xv = xt[k][r];
      const float* wk = wb + (size_t)k * WCOLS;
      float4 w0 = *(const float4*)(wk + 0);
      float4 w1 = *(const float4*)(wk + 4);
      float4 w2 = *(const float4*)(wk + 8);
      float4 w3 = *(const float4*)(wk + 12);
      a0.x += xv * w0.x; a0.y += xv * w0.y; a0.z += xv * w0.z; a0.w += xv * w0.w;
      a1.x += xv * w1.x; a1.y += xv * w1.y; a1.z += xv * w1.z; a1.w += xv * w1.w;
      a2.x += xv * w2.x; a2.y += xv * w2.y; a2.z += xv * w2.z; a2.w += xv * w2.w;
      a3.x += xv * w3.x; a3.y += xv * w3.y; a3.z += xv * w3.z; a3.w += xv * w3.w;
    }
  }
  const float* br = Wt + (size_t)IND * WCOLS + cg16;
  float4 b0 = *(const float4*)(br + 0), b1 = *(const float4*)(br + 4);
  float4 b2 = *(const float4*)(br + 8), b3 = *(const float4*)(br + 12);
  a0.x += b0.x; a0.y += b0.y; a0.z += b0.z; a0.w += b0.w;
  a1.x += b1.x; a1.y += b1.y; a1.z += b1.z; a1.w += b1.w;
  a2.x += b2.x; a2.y += b2.y; a2.z += b2.z; a2.w += b2.w;
  a3.x += b3.x; a3.y += b3.y; a3.z += b3.z; a3.w += b3.w;
  float* o = GPC + (size_t)(m0 + r) * WCOLS + cg16;
  *(float4*)(o + 0) = a0; *(float4*)(o + 4)  = a1;
  *(float4*)(o + 8) = a2; *(float4*)(o + 12) = a3;
}

// ---------------- sequential scan: 1 wave per batch ----------------
__global__ __launch_bounds__(64) void k_scan(
    const float* __restrict__ GPC, const int* __restrict__ lens_raw,
    const float* __restrict__ b_out, const int* __restrict__ wsp,
    float* __restrict__ outputs, float* __restrict__ weights) {
  __shared__ __align__(16) float Pt[OD * TT];   // transposed+rotated P  (59392 B)
  __shared__ __align__(16) float w_lds[TT];     // softmax weights (absolute j)
  __shared__ __align__(16) float s_lds[TT];     // score scratch
  __shared__ __align__(16) float q_lds[32];     // [query(29) | 1 | 0 | 0]

  int b = blockIdx.x;
  int l = threadIdx.x;
  int len;
  { // int32 / int64 hedge: lens sorted desc, all >0, so word[1]==0 <=> int64
    int probe = lens_raw[1];
    len = (probe == 0) ? lens_raw[2 * b] : lens_raw[b];
  }
  if (len > TT) len = TT;
  if (len < 0) len = 0;
  int ws = wsp[0];

  const float* gb = GPC + (size_t)b * TT * WCOLS;
  // stage Pt (P cols 32..63 of GPC, transposed, float4-rotated by k), zero w_lds
  for (int j0 = 0; j0 < TT; j0 += 64) {
    int j = j0 + l;
    int j4 = j >> 2, jm = j & 3;
    const float* src = gb + (size_t)j * WCOLS + 32;
    #pragma unroll
    for (int u = 0; u < 8; ++u) {
      float4 v = *(const float4*)(src + 4 * u);
      int kb = 4 * u;
      if (kb + 0 < OD) Pt[(kb+0)*TT + (((j4 + kb+0) & 127) << 2) + jm] = v.x;
      if (kb + 1 < OD) Pt[(kb+1)*TT + (((j4 + kb+1) & 127) << 2) + jm] = v.y;
      if (kb + 2 < OD) Pt[(kb+2)*TT + (((j4 + kb+2) & 127) << 2) + jm] = v.z;
      if (kb + 3 < OD) Pt[(kb+3)*TT + (((j4 + kb+3) & 127) << 2) + jm] = v.w;
    }
    w_lds[j] = 0.f;
  }
  if (l < 32)
    q_lds[l] = (l < OD - 1) ? 1.f : (l == OD - 1 ? 9.f : (l == OD ? 1.f : 0.f));
  int k = l & 31, h = l >> 5;
  float boutk = (k < OD) ? b_out[k] : 0.f;
  __syncthreads();

  float* outb = outputs + (size_t)b * TT * OD;
  float* wb   = weights + (size_t)b * TT * TT;

  int t = 0;
  for (; t < len; ++t) {
    int jlo = t - ws; if (jlo < 0) jlo = 0;
    int jhi = t + ws; if (jhi > len - 1) jhi = len - 1;
    // query (broadcast from LDS): [query | 1 | 0 0]
    float4 q0 = *(const float4*)(q_lds + 0);
    float4 q1 = *(const float4*)(q_lds + 4);
    float4 q2 = *(const float4*)(q_lds + 8);
    float4 q3 = *(const float4*)(q_lds + 12);
    float4 q4 = *(const float4*)(q_lds + 16);
    float4 q5 = *(const float4*)(q_lds + 20);
    float4 q6 = *(const float4*)(q_lds + 24);
    float4 q7 = *(const float4*)(q_lds + 28);
    // ---- scores: s_j = query . G[j] + C[j] (scale pre-folded) ----
    float mx = -INFINITY;
    for (int j0 = jlo; j0 <= jhi; j0 += 64) {
      int j = j0 + l;
      if (j <= jhi) {
        const float4* g4 = (const float4*)(gb + (size_t)j * WCOLS);
        float acc = 0.f; float4 g;
        g = g4[0]; acc += q0.x*g.x + q0.y*g.y + q0.z*g.z + q0.w*g.w;
        g = g4[1]; acc += q1.x*g.x + q1.y*g.y + q1.z*g.z + q1.w*g.w;
        g = g4[2]; acc += q2.x*g.x + q2.y*g.y + q2.z*g.z + q2.w*g.w;
        g = g4[3]; acc += q3.x*g.x + q3.y*g.y + q3.z*g.z + q3.w*g.w;
        g = g4[4]; acc += q4.x*g.x + q4.y*g.y + q4.z*g.z + q4.w*g.w;
        g = g4[5]; acc += q5.x*g.x + q5.y*g.y + q5.z*g.z + q5.w*g.w;
        g = g4[6]; acc += q6.x*g.x + q6.y*g.y + q6.z*g.z + q6.w*g.w;
        g = g4[7]; acc += q7.x*g.x + q7.y*g.y + q7.z*g.z + q7.w*g.w;
        s_lds[j - jlo] = acc;
        mx = fmaxf(mx, acc);
      }
    }
    #pragma unroll
    for (int off = 32; off >= 1; off >>= 1) mx = fmaxf(mx, __shfl_xor(mx, off));
    // ---- softmax ----
    float sm = 0.f;
    for (int j0 = jlo; j0 <= jhi; j0 += 64) {
      int j = j0 + l;
      if (j <= jhi) {
        float e = __expf(s_lds[j - jlo] - mx);
        s_lds[j - jlo] = e;
        sm += e;
      }
    }
    #pragma unroll
    for (int off = 32; off >= 1; off >>= 1) sm += __shfl_xor(sm, off);
    float invS = 1.f / sm;
    float* wrow = wb + (size_t)t * TT;
    for (int j0 = jlo; j0 <= jhi; j0 += 64) {
      int j = j0 + l;
      if (j <= jhi) {
        float wv = s_lds[j - jlo] * invS;
        w_lds[j] = wv;
        wrow[j] = wv;
      }
    }
    if (l == 0 && jlo > 0) w_lds[jlo - 1] = 0.f;  // evict stale window entry
    __syncthreads();
    // ---- PV: nq_k = sum_j w_j * P[j][k] + b_out_k ----
    float4 a = make_float4(0, 0, 0, 0);
    if (k < OD) {
      int qlo = jlo >> 2, qhi = jhi >> 2;
      const float* pr = Pt + k * TT;
      for (int qq = qlo + h; qq <= qhi; qq += 2) {
        float4 wv = *(const float4*)(w_lds + (qq << 2));
        float4 pv = *(const float4*)(pr + (((qq + k) & 127) << 2));
        a.x += wv.x * pv.x; a.y += wv.y * pv.y;
        a.z += wv.z * pv.z; a.w += wv.w * pv.w;
      }
    }
    a.x += __shfl_xor(a.x, 32);
    a.y += __shfl_xor(a.y, 32);
    a.z += __shfl_xor(a.z, 32);
    a.w += __shfl_xor(a.w, 32);
    float nq = (a.x + a.y) + (a.z + a.w) + boutk;
    if (h == 0 && k < OD) {
      q_lds[k] = nq;
      outb[(size_t)t * OD + k] = nq;
    }
    __syncthreads();
  }
  // dead tail: outputs = b_out, weights stay zero
  for (; t < TT; ++t)
    if (l < OD) outb[(size_t)t * OD + l] = boutk;
}

extern "C" void kernel_launch(void* const* d_in, const int* in_sizes, int n_in,
                              void* d_out, int out_size, void* d_ws, size_t ws_size,
                              hipStream_t stream) {
  const float* x     = (const float*)d_in[0];
  const int*   lens  = (const int*)d_in[1];
  const float* W_in  = (const float*)d_in[2];
  const float* b_in  = (const float*)d_in[3];
  const float* W_q   = (const float*)d_in[4];
  const float* b_q   = (const float*)d_in[5];
  const float* W_out = (const float*)d_in[6];
  const float* b_out = (const float*)d_in[7];
  const int*   wsp   = (const int*)d_in[8];
  float* out = (float*)d_out;

  float* Wt  = (float*)d_ws;                      // [2049][64]
  float* GPC = Wt + (size_t)(IND + 1) * WCOLS;    // [B*T][64]

  k_zero<<<1024, 256, 0, stream>>>(out, out_size);
  k_transform<<<IND + 1, 64, 0, stream>>>(W_in, b_in, W_q, b_q, W_out, Wt);
  k_gemm<<<(BB * TT) / 64, 256, 0, stream>>>(x, Wt, GPC);

  float* outputs = out;
  float* weights = out + (size_t)BB * TT * OD;
  k_scan<<<BB, 64, 0, stream>>>(GPC, lens, b_out, wsp, outputs, weights);
}

// Round 2
// 1116.966 us; speedup vs baseline: 1.5777x; 1.5777x over previous
//
#include <hip/hip_runtime.h>
#include <math.h>

#define BB 32
#define TT 512
#define IND 2048
#define DD 512
#define OD 29
#define WCOLS 64

// ---------------- zero-fill d_out ----------------
__global__ void k_zero(float* __restrict__ p, int n) {
  int n4 = n >> 2;
  int i = blockIdx.x * blockDim.x + threadIdx.x;
  int stride = gridDim.x * blockDim.x;
  float4 z = make_float4(0.f, 0.f, 0.f, 0.f);
  for (int j = i; j < n4; j += stride) ((float4*)p)[j] = z;
  int base = (n4 << 2) + i;
  if (base < n) p[base] = 0.f;
}

// ---------------- fold weights: Wt[2049][64] ----------------
// cols 0..28 : scale * W_in @ W_q^T     (G part)
// col  29    : scale * W_in @ b_q       (C part)
// cols 32..60: W_in @ W_out             (P part)
// row 2048   : same with b_in (bias row). Other cols = 0.
__global__ __launch_bounds__(64) void k_transform(
    const float* __restrict__ W_in, const float* __restrict__ b_in,
    const float* __restrict__ W_q,  const float* __restrict__ b_q,
    const float* __restrict__ W_out, float* __restrict__ Wt) {
  int i = blockIdx.x;          // 0..2048
  int c = threadIdx.x;         // 0..63
  const float* row = (i < IND) ? (W_in + (size_t)i * DD) : b_in;
  const float* m;
  int strd;
  bool valid = true, dscale = false;
  if (c < OD)                { m = W_q + (size_t)c * DD; strd = 1; dscale = true; }
  else if (c == OD)          { m = b_q;                  strd = 1; dscale = true; }
  else if (c >= 32 && c < 32 + OD) { m = W_out + (c - 32); strd = OD; }
  else                       { m = b_q; strd = 0; valid = false; }
  float a0 = 0.f, a1 = 0.f, a2 = 0.f, a3 = 0.f;
  for (int d = 0; d < DD; d += 4) {
    a0 += row[d + 0] * m[(size_t)(d + 0) * strd];
    a1 += row[d + 1] * m[(size_t)(d + 1) * strd];
    a2 += row[d + 2] * m[(size_t)(d + 2) * strd];
    a3 += row[d + 3] * m[(size_t)(d + 3) * strd];
  }
  float acc = (a0 + a1) + (a2 + a3);
  if (dscale) acc *= (1.0f / sqrtf((float)DD));
  if (!valid) acc = 0.f;
  Wt[(size_t)i * WCOLS + c] = acc;
}

// ---------------- GPC = x @ Wt + bias ----------------
__global__ __launch_bounds__(256) void k_gemm(
    const float* __restrict__ x, const float* __restrict__ Wt,
    float* __restrict__ GPC) {
  __shared__ float xt[128][65];
  int tid = threadIdx.x;
  int r = tid & 63;
  int cg16 = __builtin_amdgcn_readfirstlane((tid >> 6) << 4);
  int m0 = blockIdx.x << 6;
  int lr = tid >> 2, lc = tid & 3;
  const float* xl = x + (size_t)(m0 + lr) * IND;
  float4 a0 = make_float4(0,0,0,0), a1 = a0, a2 = a0, a3 = a0;
  for (int kk = 0; kk < IND; kk += 128) {
    __syncthreads();
    #pragma unroll
    for (int j = 0; j < 8; ++j) {
      int k = (lc + 4 * j) << 2;
      float4 v = *(const float4*)(xl + kk + k);
      xt[k + 0][lr] = v.x; xt[k + 1][lr] = v.y;
      xt[k + 2][lr] = v.z; xt[k + 3][lr] = v.w;
    }
    __syncthreads();
    const float* wb = Wt + (size_t)kk * WCOLS + cg16;
    #pragma unroll 4
    for (int k = 0; k < 128; ++k) {
      float xv = xt[k][r];
      const float* wk = wb + (size_t)k * WCOLS;
      float4 w0 = *(const float4*)(wk + 0);
      float4 w1 = *(const float4*)(wk + 4);
      float4 w2 = *(const float4*)(wk + 8);
      float4 w3 = *(const float4*)(wk + 12);
      a0.x += xv * w0.x; a0.y += xv * w0.y; a0.z += xv * w0.z; a0.w += xv * w0.w;
      a1.x += xv * w1.x; a1.y += xv * w1.y; a1.z += xv * w1.z; a1.w += xv * w1.w;
      a2.x += xv * w2.x; a2.y += xv * w2.y; a2.z += xv * w2.z; a2.w += xv * w2.w;
      a3.x += xv * w3.x; a3.y += xv * w3.y; a3.z += xv * w3.z; a3.w += xv * w3.w;
    }
  }
  const float* br = Wt + (size_t)IND * WCOLS + cg16;
  float4 b0 = *(const float4*)(br + 0), b1 = *(const float4*)(br + 4);
  float4 b2 = *(const float4*)(br + 8), b3 = *(const float4*)(br + 12);
  a0.x += b0.x; a0.y += b0.y; a0.z += b0.z; a0.w += b0.w;
  a1.x += b1.x; a1.y += b1.y; a1.z += b1.z; a1.w += b1.w;
  a2.x += b2.x; a2.y += b2.y; a2.z += b2.z; a2.w += b2.w;
  a3.x += b3.x; a3.y += b3.y; a3.z += b3.z; a3.w += b3.w;
  float* o = GPC + (size_t)(m0 + r) * WCOLS + cg16;
  *(float4*)(o + 0) = a0; *(float4*)(o + 4)  = a1;
  *(float4*)(o + 8) = a2; *(float4*)(o + 12) = a3;
}

// ---------------- scan helpers ----------------
__device__ __forceinline__ void ld_g(float4* g, const float* gb, int j) {
  const float4* s = (const float4*)(gb + (size_t)j * WCOLS);
  #pragma unroll
  for (int u = 0; u < 8; ++u) g[u] = s[u];
}

__device__ __forceinline__ float score_dot(const float4* g, const float* qs) {
  // cols 0..28 = G, col 29 (g[7].y) = C, cols 30/31 = 0
  float a0 = g[7].y, a1 = 0.f, a2 = 0.f, a3 = 0.f;
  a0 += qs[0]  * g[0].x; a1 += qs[1]  * g[0].y; a2 += qs[2]  * g[0].z; a3 += qs[3]  * g[0].w;
  a0 += qs[4]  * g[1].x; a1 += qs[5]  * g[1].y; a2 += qs[6]  * g[1].z; a3 += qs[7]  * g[1].w;
  a0 += qs[8]  * g[2].x; a1 += qs[9]  * g[2].y; a2 += qs[10] * g[2].z; a3 += qs[11] * g[2].w;
  a0 += qs[12] * g[3].x; a1 += qs[13] * g[3].y; a2 += qs[14] * g[3].z; a3 += qs[15] * g[3].w;
  a0 += qs[16] * g[4].x; a1 += qs[17] * g[4].y; a2 += qs[18] * g[4].z; a3 += qs[19] * g[4].w;
  a0 += qs[20] * g[5].x; a1 += qs[21] * g[5].y; a2 += qs[22] * g[5].z; a3 += qs[23] * g[5].w;
  a0 += qs[24] * g[6].x; a1 += qs[25] * g[6].y; a2 += qs[26] * g[6].z; a3 += qs[27] * g[6].w;
  a0 += qs[28] * g[7].x;
  return (a0 + a1) + (a2 + a3);
}

// ---------------- sequential scan: 1 wave per batch, no barriers ----------------
__global__ __launch_bounds__(64) void k_scan(
    const float* __restrict__ GPC, const int* __restrict__ lens_raw,
    const float* __restrict__ b_out, const int* __restrict__ wsp,
    float* __restrict__ outputs, float* __restrict__ weights) {
  __shared__ __align__(16) float Pt[OD * TT];   // transposed+rotated P (59392 B)
  __shared__ __align__(16) float w_lds[640];    // softmax weights, zero-padded

  int b = blockIdx.x;
  int l = threadIdx.x;
  int len;
  { // int32 / int64 hedge: lens sorted desc, all >0, so word[1]==0 <=> int64
    int probe = lens_raw[1];
    len = (probe == 0) ? lens_raw[2 * b] : lens_raw[b];
  }
  if (len > TT) len = TT;
  if (len < 0) len = 0;
  int ws = wsp[0];

  const float* gb = GPC + (size_t)b * TT * WCOLS;
  // stage Pt (P = cols 32..60 of GPC, transposed, float4-rotated by k)
  for (int j0 = 0; j0 < TT; j0 += 64) {
    int j = j0 + l;
    int j4 = j >> 2, jm = j & 3;
    const float* src = gb + (size_t)j * WCOLS + 32;
    #pragma unroll
    for (int u = 0; u < 8; ++u) {
      float4 v = *(const float4*)(src + 4 * u);
      int kb = 4 * u;
      if (kb + 0 < OD) Pt[(kb+0)*TT + (((j4 + kb+0) & 127) << 2) + jm] = v.x;
      if (kb + 1 < OD) Pt[(kb+1)*TT + (((j4 + kb+1) & 127) << 2) + jm] = v.y;
      if (kb + 2 < OD) Pt[(kb+2)*TT + (((j4 + kb+2) & 127) << 2) + jm] = v.z;
      if (kb + 3 < OD) Pt[(kb+3)*TT + (((j4 + kb+3) & 127) << 2) + jm] = v.w;
    }
  }
  for (int j = l; j < 640; j += 64) w_lds[j] = 0.f;
  __syncthreads();

  int k = l & 31, h = l >> 5;
  float boutk = (k < OD) ? b_out[k] : 0.f;

  float* outb = outputs + (size_t)b * TT * OD;
  float* wb   = weights + (size_t)b * TT * TT;

  // query state as uniform registers; init_strategy='fix': ones, last = 9
  float qs[OD];
  #pragma unroll
  for (int i = 0; i < OD - 1; ++i) qs[i] = 1.f;
  qs[OD - 1] = 9.f;

  // prefetch G rows for t = 0
  int jlo = 0;
  int jhi = (ws < len - 1) ? ws : (len - 1);
  float4 gA[8], gB[8], gC[8];
  {
    int jA = jlo + l;        if (jA > TT - 1) jA = TT - 1;
    int jB = jlo + 64 + l;   if (jB > TT - 1) jB = TT - 1;
    int jC = jlo + 128;      if (jC > TT - 1) jC = TT - 1;
    ld_g(gA, gb, jA); ld_g(gB, gb, jB); ld_g(gC, gb, jC);
  }

  int t = 0;
  for (; t < len; ++t) {
    int jA = jlo + l, jB = jlo + 64 + l, jC = jlo + 128;
    bool vA = (jA <= jhi), vB = (jB <= jhi), vCm = (jC <= jhi);
    // ---- scores (G in registers, q uniform) ----
    float sA = score_dot(gA, qs);
    float sB = score_dot(gB, qs);
    float sC = score_dot(gC, qs);
    const float NEG = -3.0e38f;
    float mx = fmaxf(fmaxf(vA ? sA : NEG, vB ? sB : NEG), vCm ? sC : NEG);
    #pragma unroll
    for (int off = 32; off >= 1; off >>= 1) mx = fmaxf(mx, __shfl_xor(mx, off));
    float eA = vA  ? __expf(sA - mx) : 0.f;
    float eB = vB  ? __expf(sB - mx) : 0.f;
    float eC = vCm ? __expf(sC - mx) : 0.f;
    float sm = eA + eB + ((l == 0) ? eC : 0.f);
    #pragma unroll
    for (int off = 32; off >= 1; off >>= 1) sm += __shfl_xor(sm, off);
    float invS = 1.f / sm;
    float wA = eA * invS, wB = eB * invS, wC = eC * invS;
    float* wrow = wb + (size_t)t * TT;
    if (l == 0 && jlo > 0) w_lds[jlo - 1] = 0.f;  // evict stale window entry
    if (vA) { w_lds[jA] = wA; wrow[jA] = wA; }
    if (vB) { w_lds[jB] = wB; wrow[jB] = wB; }
    if (vCm && l == 0) { w_lds[jC] = wC; wrow[jC] = wC; }
    // ---- prefetch G for t+1 (latency hides under PV) ----
    int jlo_n = (t + 1) - ws; if (jlo_n < 0) jlo_n = 0;
    int jhi_n = (t + 1) + ws; if (jhi_n > len - 1) jhi_n = len - 1;
    {
      int nA = jlo_n + l;       if (nA > TT - 1) nA = TT - 1;
      int nB = jlo_n + 64 + l;  if (nB > TT - 1) nB = TT - 1;
      int nC = jlo_n + 128;     if (nC > TT - 1) nC = TT - 1;
      ld_g(gA, gb, nA); ld_g(gB, gb, nB); ld_g(gC, gb, nC);
    }
    // single-wave LDS hand-off: wait DS ops only (no vmcnt drain!)
    asm volatile("s_waitcnt lgkmcnt(0)" ::: "memory");
    // ---- PV: nq_k = sum_j w_j * P[j][k] + b_out_k ----
    float4 a = make_float4(0, 0, 0, 0);
    int qlo = jlo >> 2;
    if (k < OD) {
      const float* pr = Pt + k * TT;
      #pragma unroll
      for (int i = 0; i < 17; ++i) {
        int qq = qlo + h + (i << 1);
        float4 wv = *(const float4*)(w_lds + (qq << 2));
        float4 pv = *(const float4*)(pr + (((qq + k) & 127) << 2));
        a.x += wv.x * pv.x; a.y += wv.y * pv.y;
        a.z += wv.z * pv.z; a.w += wv.w * pv.w;
      }
    }
    a.x += __shfl_xor(a.x, 32);
    a.y += __shfl_xor(a.y, 32);
    a.z += __shfl_xor(a.z, 32);
    a.w += __shfl_xor(a.w, 32);
    float nq = (a.x + a.y) + (a.z + a.w) + boutk;
    if (h == 0 && k < OD) outb[(size_t)t * OD + k] = nq;
    // broadcast new query into uniform registers
    #pragma unroll
    for (int kk = 0; kk < OD; ++kk)
      qs[kk] = __int_as_float(__builtin_amdgcn_readlane(__float_as_int(nq), kk));
    jlo = jlo_n; jhi = jhi_n;
  }
  // dead tail: outputs = b_out, weights stay zero
  for (; t < TT; ++t)
    if (l < OD) outb[(size_t)t * OD + l] = boutk;
}

extern "C" void kernel_launch(void* const* d_in, const int* in_sizes, int n_in,
                              void* d_out, int out_size, void* d_ws, size_t ws_size,
                              hipStream_t stream) {
  const float* x     = (const float*)d_in[0];
  const int*   lens  = (const int*)d_in[1];
  const float* W_in  = (const float*)d_in[2];
  const float* b_in  = (const float*)d_in[3];
  const float* W_q   = (const float*)d_in[4];
  const float* b_q   = (const float*)d_in[5];
  const float* W_out = (const float*)d_in[6];
  const float* b_out = (const float*)d_in[7];
  const int*   wsp   = (const int*)d_in[8];
  float* out = (float*)d_out;

  float* Wt  = (float*)d_ws;                      // [2049][64]
  float* GPC = Wt + (size_t)(IND + 1) * WCOLS;    // [B*T][64]

  k_zero<<<1024, 256, 0, stream>>>(out, out_size);
  k_transform<<<IND + 1, 64, 0, stream>>>(W_in, b_in, W_q, b_q, W_out, Wt);
  k_gemm<<<(BB * TT) / 64, 256, 0, stream>>>(x, Wt, GPC);

  float* outputs = out;
  float* weights = out + (size_t)BB * TT * OD;
  k_scan<<<BB, 64, 0, stream>>>(GPC, lens, b_out, wsp, outputs, weights);
}

// Round 3
// 1063.097 us; speedup vs baseline: 1.6577x; 1.0507x over previous
//
#include <hip/hip_runtime.h>
#include <math.h>

#define BB 32
#define TT 512
#define IND 2048
#define DD 512
#define OD 29
#define WCOLS 64

typedef float v2f __attribute__((ext_vector_type(2)));

__device__ __forceinline__ v2f pk_fma(v2f a, v2f b, v2f c) {
  v2f d;
  asm("v_pk_fma_f32 %0, %1, %2, %3" : "=v"(d) : "v"(a), "v"(b), "v"(c));
  return d;
}

template<int CTRL, int RM>
__device__ __forceinline__ float updpp(float idv, float x) {
  return __int_as_float(__builtin_amdgcn_update_dpp(
      __float_as_int(idv), __float_as_int(x), CTRL, RM, 0xf, false));
}

// All-VALU wave64 reductions: quad_perm xor1/xor2, row_ror 4/8 (row totals),
// then scan-style row_bcast15/31 (lane 63 ends with full total), readlane 63.
__device__ __forceinline__ float red_max64(float x) {
  const float ID = -3.0e38f;
  x = fmaxf(x, updpp<0xB1, 0xf>(ID, x));
  x = fmaxf(x, updpp<0x4E, 0xf>(ID, x));
  x = fmaxf(x, updpp<0x124, 0xf>(ID, x));
  x = fmaxf(x, updpp<0x128, 0xf>(ID, x));
  x = fmaxf(x, updpp<0x142, 0xa>(ID, x));
  x = fmaxf(x, updpp<0x143, 0xc>(ID, x));
  return __int_as_float(__builtin_amdgcn_readlane(__float_as_int(x), 63));
}

__device__ __forceinline__ float red_sum64(float x) {
  x += updpp<0xB1, 0xf>(0.f, x);
  x += updpp<0x4E, 0xf>(0.f, x);
  x += updpp<0x124, 0xf>(0.f, x);
  x += updpp<0x128, 0xf>(0.f, x);
  x += updpp<0x142, 0xa>(0.f, x);
  x += updpp<0x143, 0xc>(0.f, x);
  return __int_as_float(__builtin_amdgcn_readlane(__float_as_int(x), 63));
}

// ---------------- zero-fill d_out ----------------
__global__ void k_zero(float* __restrict__ p, int n) {
  int n4 = n >> 2;
  int i = blockIdx.x * blockDim.x + threadIdx.x;
  int stride = gridDim.x * blockDim.x;
  float4 z = make_float4(0.f, 0.f, 0.f, 0.f);
  for (int j = i; j < n4; j += stride) ((float4*)p)[j] = z;
  int base = (n4 << 2) + i;
  if (base < n) p[base] = 0.f;
}

// ---------------- fold weights: Wt[2049][64] ----------------
__global__ __launch_bounds__(64) void k_transform(
    const float* __restrict__ W_in, const float* __restrict__ b_in,
    const float* __restrict__ W_q,  const float* __restrict__ b_q,
    const float* __restrict__ W_out, float* __restrict__ Wt) {
  int i = blockIdx.x;          // 0..2048
  int c = threadIdx.x;         // 0..63
  const float* row = (i < IND) ? (W_in + (size_t)i * DD) : b_in;
  const float* m;
  int strd;
  bool valid = true, dscale = false;
  if (c < OD)                { m = W_q + (size_t)c * DD; strd = 1; dscale = true; }
  else if (c == OD)          { m = b_q;                  strd = 1; dscale = true; }
  else if (c >= 32 && c < 32 + OD) { m = W_out + (c - 32); strd = OD; }
  else                       { m = b_q; strd = 0; valid = false; }
  float a0 = 0.f, a1 = 0.f, a2 = 0.f, a3 = 0.f;
  for (int d = 0; d < DD; d += 4) {
    a0 += row[d + 0] * m[(size_t)(d + 0) * strd];
    a1 += row[d + 1] * m[(size_t)(d + 1) * strd];
    a2 += row[d + 2] * m[(size_t)(d + 2) * strd];
    a3 += row[d + 3] * m[(size_t)(d + 3) * strd];
  }
  float acc = (a0 + a1) + (a2 + a3);
  if (dscale) acc *= (1.0f / sqrtf((float)DD));
  if (!valid) acc = 0.f;
  Wt[(size_t)i * WCOLS + c] = acc;
}

// ---------------- GPC = x @ Wt + bias ----------------
__global__ __launch_bounds__(256) void k_gemm(
    const float* __restrict__ x, const float* __restrict__ Wt,
    float* __restrict__ GPC) {
  __shared__ float xt[128][65];
  int tid = threadIdx.x;
  int r = tid & 63;
  int cg16 = __builtin_amdgcn_readfirstlane((tid >> 6) << 4);
  int m0 = blockIdx.x << 6;
  int lr = tid >> 2, lc = tid & 3;
  const float* xl = x + (size_t)(m0 + lr) * IND;
  float4 a0 = make_float4(0,0,0,0), a1 = a0, a2 = a0, a3 = a0;
  for (int kk = 0; kk < IND; kk += 128) {
    __syncthreads();
    #pragma unroll
    for (int j = 0; j < 8; ++j) {
      int k = (lc + 4 * j) << 2;
      float4 v = *(const float4*)(xl + kk + k);
      xt[k + 0][lr] = v.x; xt[k + 1][lr] = v.y;
      xt[k + 2][lr] = v.z; xt[k + 3][lr] = v.w;
    }
    __syncthreads();
    const float* wb = Wt + (size_t)kk * WCOLS + cg16;
    #pragma unroll 4
    for (int k = 0; k < 128; ++k) {
      float xv = xt[k][r];
      const float* wk = wb + (size_t)k * WCOLS;
      float4 w0 = *(const float4*)(wk + 0);
      float4 w1 = *(const float4*)(wk + 4);
      float4 w2 = *(const float4*)(wk + 8);
      float4 w3 = *(const float4*)(wk + 12);
      a0.x += xv * w0.x; a0.y += xv * w0.y; a0.z += xv * w0.z; a0.w += xv * w0.w;
      a1.x += xv * w1.x; a1.y += xv * w1.y; a1.z += xv * w1.z; a1.w += xv * w1.w;
      a2.x += xv * w2.x; a2.y += xv * w2.y; a2.z += xv * w2.z; a2.w += xv * w2.w;
      a3.x += xv * w3.x; a3.y += xv * w3.y; a3.z += xv * w3.z; a3.w += xv * w3.w;
    }
  }
  const float* br = Wt + (size_t)IND * WCOLS + cg16;
  float4 b0 = *(const float4*)(br + 0), b1 = *(const float4*)(br + 4);
  float4 b2 = *(const float4*)(br + 8), b3 = *(const float4*)(br + 12);
  a0.x += b0.x; a0.y += b0.y; a0.z += b0.z; a0.w += b0.w;
  a1.x += b1.x; a1.y += b1.y; a1.z += b1.z; a1.w += b1.w;
  a2.x += b2.x; a2.y += b2.y; a2.z += b2.z; a2.w += b2.w;
  a3.x += b3.x; a3.y += b3.y; a3.z += b3.z; a3.w += b3.w;
  float* o = GPC + (size_t)(m0 + r) * WCOLS + cg16;
  *(float4*)(o + 0) = a0; *(float4*)(o + 4)  = a1;
  *(float4*)(o + 8) = a2; *(float4*)(o + 12) = a3;
}

// ---------------- scan helpers ----------------
__device__ __forceinline__ void ld_g(v2f* g, const float* gb, int j) {
  const float4* s = (const float4*)(gb + (size_t)j * WCOLS);
  #pragma unroll
  for (int u = 0; u < 8; ++u) {
    float4 v = s[u];
    g[2*u+0] = (v2f){v.x, v.y};
    g[2*u+1] = (v2f){v.z, v.w};
  }
}

// pairs 0..14 cover cols 0..29 (col 29 = C, paired against q-slot 1.0)
__device__ __forceinline__ float score_pk(const v2f* g, const v2f* qp) {
  v2f a0 = pk_fma(qp[0], g[0], (v2f){0.f, 0.f});
  v2f a1 = pk_fma(qp[1], g[1], (v2f){0.f, 0.f});
  v2f a2 = pk_fma(qp[2], g[2], (v2f){0.f, 0.f});
  #pragma unroll
  for (int i = 3; i < 15; i += 3) {
    a0 = pk_fma(qp[i+0], g[i+0], a0);
    a1 = pk_fma(qp[i+1], g[i+1], a1);
    a2 = pk_fma(qp[i+2], g[i+2], a2);
  }
  v2f s = a0 + a1;
  s = s + a2;
  return s.x + s.y;
}

// ---------------- sequential scan: 1 wave per batch, no barriers ----------------
__global__ __launch_bounds__(64) void k_scan(
    const float* __restrict__ GPC, const int* __restrict__ lens_raw,
    const float* __restrict__ b_out, const int* __restrict__ wsp,
    float* __restrict__ outputs, float* __restrict__ weights) {
  __shared__ __align__(16) float Pt[OD * TT];   // transposed+rotated P (59392 B)
  __shared__ __align__(16) float w_lds[640];    // unnormalized e, zero-padded

  int b = blockIdx.x;
  int l = threadIdx.x;
  int len;
  { // int32 / int64 hedge: lens sorted desc, all >0, so word[1]==0 <=> int64
    int probe = lens_raw[1];
    len = (probe == 0) ? lens_raw[2 * b] : lens_raw[b];
  }
  if (len > TT) len = TT;
  if (len < 0) len = 0;
  int ws = wsp[0];

  const float* gb = GPC + (size_t)b * TT * WCOLS;
  // stage Pt (P = cols 32..60 of GPC, transposed, float4-rotated by k)
  for (int j0 = 0; j0 < TT; j0 += 64) {
    int j = j0 + l;
    int j4 = j >> 2, jm = j & 3;
    const float* src = gb + (size_t)j * WCOLS + 32;
    #pragma unroll
    for (int u = 0; u < 8; ++u) {
      float4 v = *(const float4*)(src + 4 * u);
      int kb = 4 * u;
      if (kb + 0 < OD) Pt[(kb+0)*TT + (((j4 + kb+0) & 127) << 2) + jm] = v.x;
      if (kb + 1 < OD) Pt[(kb+1)*TT + (((j4 + kb+1) & 127) << 2) + jm] = v.y;
      if (kb + 2 < OD) Pt[(kb+2)*TT + (((j4 + kb+2) & 127) << 2) + jm] = v.z;
      if (kb + 3 < OD) Pt[(kb+3)*TT + (((j4 + kb+3) & 127) << 2) + jm] = v.w;
    }
  }
  for (int j = l; j < 640; j += 64) w_lds[j] = 0.f;
  __syncthreads();

  int k = l & 31, h = l >> 5;
  float boutk = (k < OD) ? b_out[k] : 0.f;

  float* outb = outputs + (size_t)b * TT * OD;
  float* wb   = weights + (size_t)b * TT * TT;

  // query as packed uniform pairs; init 'fix': ones, last channel = 9
  v2f qp[15];
  #pragma unroll
  for (int i = 0; i < 14; ++i) qp[i] = (v2f){1.f, 1.f};
  qp[14] = (v2f){9.f, 1.f};

  // prefetch G rows for t = 0
  int jlo = 0;
  int jhi = (ws < len - 1) ? ws : (len - 1);
  v2f gA[16], gB[16], gC[16];
  {
    int jA = jlo + l;        if (jA > TT - 1) jA = TT - 1;
    int jB = jlo + 64 + l;   if (jB > TT - 1) jB = TT - 1;
    int jC = jlo + 128;      if (jC > TT - 1) jC = TT - 1;
    ld_g(gA, gb, jA); ld_g(gB, gb, jB); ld_g(gC, gb, jC);
  }

  int t = 0;
  for (; t < len; ++t) {
    int jA = jlo + l, jB = jlo + 64 + l, jC = jlo + 128;
    bool vA = (jA <= jhi), vB = (jB <= jhi), vCm = (jC <= jhi);
    // ---- scores (packed f32 FMA, q uniform) ----
    float sA = score_pk(gA, qp);
    float sB = score_pk(gB, qp);
    float sC = score_pk(gC, qp);
    const float NEG = -3.0e38f;
    float mx0 = fmaxf(fmaxf(vA ? sA : NEG, vB ? sB : NEG), vCm ? sC : NEG);
    float mx = red_max64(mx0);                    // all-VALU ladder
    float eA = vA  ? __expf(sA - mx) : 0.f;
    float eB = vB  ? __expf(sB - mx) : 0.f;
    float eC = vCm ? __expf(sC - mx) : 0.f;
    // unnormalized e into LDS for PV
    if (l == 0 && jlo > 0) w_lds[jlo - 1] = 0.f;  // evict stale window entry
    if (vA) w_lds[jA] = eA;
    if (vB) w_lds[jB] = eB;
    if (vCm && l == 0) w_lds[jC] = eC;
    // ---- prefetch G for t+1 (latency hides under PV) ----
    int jlo_n = (t + 1) - ws; if (jlo_n < 0) jlo_n = 0;
    int jhi_n = (t + 1) + ws; if (jhi_n > len - 1) jhi_n = len - 1;
    {
      int nA = jlo_n + l;       if (nA > TT - 1) nA = TT - 1;
      int nB = jlo_n + 64 + l;  if (nB > TT - 1) nB = TT - 1;
      int nC = jlo_n + 128;     if (nC > TT - 1) nC = TT - 1;
      ld_g(gA, gb, nA); ld_g(gB, gb, nB); ld_g(gC, gb, nC);
    }
    // sum reduce + rcp overlap with PV issue below (off the LDS path)
    float sm = red_sum64(eA + eB + ((l == 0) ? eC : 0.f));
    float invS = __builtin_amdgcn_rcpf(sm);
    // single-wave LDS hand-off: wait DS ops only (no vmcnt drain!)
    asm volatile("s_waitcnt lgkmcnt(0)" ::: "memory");
    // ---- PV on unnormalized e: nq_k = invS * sum_j e_j P[j][k] + b_out_k ----
    v2f p01 = (v2f){0.f, 0.f}, p23 = (v2f){0.f, 0.f};
    int qlo = jlo >> 2;
    if (k < OD) {
      const float* pr = Pt + k * TT;
      #pragma unroll
      for (int i = 0; i < 17; ++i) {
        int qq = qlo + h + (i << 1);
        float4 wv = *(const float4*)(w_lds + (qq << 2));
        float4 pv = *(const float4*)(pr + (((qq + k) & 127) << 2));
        p01 = pk_fma((v2f){wv.x, wv.y}, (v2f){pv.x, pv.y}, p01);
        p23 = pk_fma((v2f){wv.z, wv.w}, (v2f){pv.z, pv.w}, p23);
      }
    }
    float tot = (p01.x + p01.y) + (p23.x + p23.y);
    tot += __shfl_xor(tot, 32);                   // single cross-half combine
    float nq = tot * invS + boutk;
    if (h == 0 && k < OD) outb[(size_t)t * OD + k] = nq;
    // normalized weights to global (off-chain)
    float* wrow = wb + (size_t)t * TT;
    if (vA) wrow[jA] = eA * invS;
    if (vB) wrow[jB] = eB * invS;
    if (vCm && l == 0) wrow[jC] = eC * invS;
    // broadcast new query into packed uniform pairs
    #pragma unroll
    for (int kk = 0; kk < 14; ++kk) {
      float lo = __int_as_float(__builtin_amdgcn_readlane(__float_as_int(nq), 2*kk));
      float hi = __int_as_float(__builtin_amdgcn_readlane(__float_as_int(nq), 2*kk+1));
      qp[kk] = (v2f){lo, hi};
    }
    qp[14] = (v2f){__int_as_float(__builtin_amdgcn_readlane(__float_as_int(nq), 28)), 1.0f};
    jlo = jlo_n; jhi = jhi_n;
  }
  // dead tail: outputs = b_out, weights stay zero
  for (; t < TT; ++t)
    if (l < OD) outb[(size_t)t * OD + l] = boutk;
}

extern "C" void kernel_launch(void* const* d_in, const int* in_sizes, int n_in,
                              void* d_out, int out_size, void* d_ws, size_t ws_size,
                              hipStream_t stream) {
  const float* x     = (const float*)d_in[0];
  const int*   lens  = (const int*)d_in[1];
  const float* W_in  = (const float*)d_in[2];
  const float* b_in  = (const float*)d_in[3];
  const float* W_q   = (const float*)d_in[4];
  const float* b_q   = (const float*)d_in[5];
  const float* W_out = (const float*)d_in[6];
  const float* b_out = (const float*)d_in[7];
  const int*   wsp   = (const int*)d_in[8];
  float* out = (float*)d_out;

  float* Wt  = (float*)d_ws;                      // [2049][64]
  float* GPC = Wt + (size_t)(IND + 1) * WCOLS;    // [B*T][64]

  k_zero<<<1024, 256, 0, stream>>>(out, out_size);
  k_transform<<<IND + 1, 64, 0, stream>>>(W_in, b_in, W_q, b_q, W_out, Wt);
  k_gemm<<<(BB * TT) / 64, 256, 0, stream>>>(x, Wt, GPC);

  float* outputs = out;
  float* weights = out + (size_t)BB * TT * OD;
  k_scan<<<BB, 64, 0, stream>>>(GPC, lens, b_out, wsp, outputs, weights);
}